// Round 1
// baseline (737.366 us; speedup 1.0000x reference)
//
#include <hip/hip_runtime.h>
#include <math.h>

#define Cc 128
#define Hh 128
#define Ww 128
#define Bb 8
#define HW 16384
#define NPIX 131072   // B*H*W
#define NOFF 18

// ---------------- K0: repack offset-conv weights to (c, o, k) contiguous ----------------
__global__ __launch_bounds__(256) void k_repack(const float* __restrict__ w_off, float* __restrict__ wp){
  int i = blockIdx.x*256 + threadIdx.x;
  if (i >= NOFF*Cc*9) return;
  int k = i % 9; int t = i / 9; int o = t % NOFF; int c = t / NOFF;
  wp[i] = w_off[(o*Cc + c)*9 + k];
}

// ---------------- K1: offset conv (Cin=128 -> 18, 3x3, pad 1) ----------------
__global__ __launch_bounds__(256) void k_offset(const float* __restrict__ x, const float* __restrict__ wp,
                                                const float* __restrict__ b_off, float* __restrict__ off){
  int idx = blockIdx.x*256 + threadIdx.x;
  int b = idx >> 14; int rem = idx & 16383; int h = rem >> 7; int w = rem & 127;

  int ofs[9]; float vm[9];
  #pragma unroll
  for (int t=0;t<9;t++){
    int hh = h + t/3 - 1, ww = w + t%3 - 1;
    bool v = (hh>=0)&&(hh<Hh)&&(ww>=0)&&(ww<Ww);
    ofs[t] = v ? (hh*Ww + ww) : 0;
    vm[t]  = v ? 1.f : 0.f;
  }
  float acc[NOFF];
  #pragma unroll
  for (int o=0;o<NOFF;o++) acc[o] = b_off[o];

  const float* xb = x + (size_t)b*Cc*HW;
  for (int c=0;c<Cc;c++){
    const float* xc = xb + c*HW;
    float xv[9];
    #pragma unroll
    for (int t=0;t<9;t++) xv[t] = xc[ofs[t]] * vm[t];
    const float* wc = wp + c*(NOFF*9);   // uniform address -> scalar loads
    #pragma unroll
    for (int o=0;o<NOFF;o++){
      float a = acc[o];
      #pragma unroll
      for (int k=0;k<9;k++) a = fmaf(xv[k], wc[o*9+k], a);
      acc[o] = a;
    }
  }
  #pragma unroll
  for (int o=0;o<NOFF;o++) off[((size_t)b*NOFF + o)*HW + rem] = acc[o];
}

// ---------------- K2: deformable depthwise conv, writes out_dw into d_out ----------------
__global__ __launch_bounds__(256) void k_deform(const float* __restrict__ x, const float* __restrict__ off,
                                                const float* __restrict__ w_dw, float* __restrict__ out){
  int idx = blockIdx.x*256 + threadIdx.x;
  int b = idx >> 14; int rem = idx & 16383; int h = rem >> 7; int w = rem & 127;

  int   io[36];
  float cf[36];
  const float* offb = off + (size_t)b*NOFF*HW;
  #pragma unroll
  for (int kk=0;kk<9;kk++){
    float oy = offb[(kk*2+0)*HW + rem];
    float ox = offb[(kk*2+1)*HW + rem];
    float py = (float)(h + kk/3 - 1) + oy;
    float px = (float)(w + kk%3 - 1) + ox;
    float fy = floorf(py), fx = floorf(px);
    float ty = py - fy, tx = px - fx;
    int y0 = (int)fy, x0 = (int)fx;
    float wy[2] = {1.f - ty, ty};
    float wx[2] = {1.f - tx, tx};
    #pragma unroll
    for (int cy=0;cy<2;cy++){
      #pragma unroll
      for (int cx=0;cx<2;cx++){
        int yy = y0+cy, xx = x0+cx;
        bool v = (yy>=0)&&(yy<Hh)&&(xx>=0)&&(xx<Ww);
        int yc = min(max(yy,0),Hh-1), xc = min(max(xx,0),Ww-1);
        io[kk*4+cy*2+cx] = yc*Ww + xc;
        cf[kk*4+cy*2+cx] = v ? wy[cy]*wx[cx] : 0.f;
      }
    }
  }

  const float* xb = x + (size_t)b*Cc*HW;
  float*       ob = out + (size_t)b*Cc*HW;
  for (int c=0;c<Cc;c++){
    const float* xc = xb + c*HW;
    const float* wd = w_dw + c*9;        // uniform -> scalar loads
    float o = 0.f;
    #pragma unroll
    for (int kk=0;kk<9;kk++){
      float s =      cf[kk*4+0]* xc[io[kk*4+0]];
      s = fmaf(cf[kk*4+1], xc[io[kk*4+1]], s);
      s = fmaf(cf[kk*4+2], xc[io[kk*4+2]], s);
      s = fmaf(cf[kk*4+3], xc[io[kk*4+3]], s);
      o = fmaf(wd[kk], s, o);
    }
    ob[c*HW + rem] = o;
  }
}

// ---------------- K2b: per-channel mean / rstd (deterministic, no atomics) ----------------
__global__ __launch_bounds__(256) void k_stats(const float* __restrict__ dw, float* __restrict__ mr){
  int c = blockIdx.x;
  float s = 0.f, s2 = 0.f;
  for (int b=0;b<Bb;b++){
    const float* p = dw + ((size_t)b*Cc + c)*HW;
    for (int i=threadIdx.x; i<HW; i+=256){ float v = p[i]; s += v; s2 = fmaf(v, v, s2); }
  }
  #pragma unroll
  for (int d=32; d>0; d>>=1){ s += __shfl_down(s, d, 64); s2 += __shfl_down(s2, d, 64); }
  __shared__ float ls[4], ls2[4];
  int lane = threadIdx.x & 63, wid = threadIdx.x >> 6;
  if (lane==0){ ls[wid]=s; ls2[wid]=s2; }
  __syncthreads();
  if (threadIdx.x==0){
    float S=0.f, S2=0.f;
    for (int i=0;i<4;i++){ S+=ls[i]; S2+=ls2[i]; }
    const float invN = 1.f/(float)(Bb*HW);
    float m = S*invN;
    float var = S2*invN - m*m;
    mr[c]      = m;
    mr[Cc + c] = rsqrtf(var + 1e-5f);
  }
}

// ---------------- K3: in-place BN-apply + SiLU + residual (float4) ----------------
__global__ __launch_bounds__(256) void k_apply(float* __restrict__ out, const float* __restrict__ x,
                                               const float* __restrict__ mr, const float* __restrict__ gamma,
                                               const float* __restrict__ beta){
  int i = blockIdx.x*256 + threadIdx.x;          // float4 index, total NPIX*Cc/4
  int c = (i >> 12) & 127;                       // (i*4 / HW) % C
  float4 v  = ((const float4*)out)[i];
  float4 xi = ((const float4*)x)[i];
  float m = mr[c], r = mr[Cc+c], g = gamma[c], be = beta[c];
  float* vp = (float*)&v; const float* xp = (const float*)&xi;
  float4 o; float* op = (float*)&o;
  #pragma unroll
  for (int j=0;j<4;j++){
    float t = (vp[j]-m)*r*g + be;
    t = t / (1.f + expf(-t));                    // SiLU
    op[j] = t + xp[j];
  }
  ((float4*)out)[i] = o;
}

extern "C" void kernel_launch(void* const* d_in, const int* in_sizes, int n_in,
                              void* d_out, int out_size, void* d_ws, size_t ws_size,
                              hipStream_t stream) {
  const float* x     = (const float*)d_in[0];
  const float* w_off = (const float*)d_in[1];
  const float* b_off = (const float*)d_in[2];
  const float* w_dw  = (const float*)d_in[3];
  const float* gamma = (const float*)d_in[4];
  const float* beta  = (const float*)d_in[5];
  float* out = (float*)d_out;

  float* wp  = (float*)d_ws;               // 20736 floats (repacked w_off)
  float* off = wp + 32768;                 // B*18*HW = 2359296 floats
  float* mr  = off + (size_t)NOFF*NPIX;    // 256 floats (mean | rstd)

  hipLaunchKernelGGL(k_repack, dim3((NOFF*Cc*9 + 255)/256), dim3(256), 0, stream, w_off, wp);
  hipLaunchKernelGGL(k_offset, dim3(NPIX/256), dim3(256), 0, stream, x, wp, b_off, off);
  hipLaunchKernelGGL(k_deform, dim3(NPIX/256), dim3(256), 0, stream, x, off, w_dw, out);
  hipLaunchKernelGGL(k_stats,  dim3(Cc),       dim3(256), 0, stream, out, mr);
  hipLaunchKernelGGL(k_apply,  dim3(NPIX*Cc/4/256), dim3(256), 0, stream, out, x, mr, gamma, beta);
}